// Round 6
// baseline (1195.600 us; speedup 1.0000x reference)
//
#include <hip/hip_runtime.h>
#include <hip/hip_bf16.h>

typedef unsigned short u16;
typedef unsigned int u32;
typedef __attribute__((ext_vector_type(4))) u32 u32x4;
typedef __attribute__((ext_vector_type(2))) u32 u32x2;
typedef __attribute__((ext_vector_type(8))) __bf16 bf16x8;
typedef __attribute__((ext_vector_type(4))) float f32x4;
typedef __attribute__((ext_vector_type(4))) short short4v;

#define HW 65536

__device__ __forceinline__ u16 f2bf(float f){
  union { u32 i; float f; } v; v.f = f;
  u32 r = v.i + 0x7fffu + ((v.i >> 16) & 1u);
  return (u16)(r >> 16);
}
__device__ __forceinline__ u32 pkbf(float a, float b){
  __bf16 lo = (__bf16)a, hi = (__bf16)b;
  u16 ulo = __builtin_bit_cast(u16, lo);
  u16 uhi = __builtin_bit_cast(u16, hi);
  return (u32)ulo | ((u32)uhi << 16);
}
__device__ __forceinline__ float rcpf(float x){
#if __has_builtin(__builtin_amdgcn_rcpf)
  return __builtin_amdgcn_rcpf(x);
#else
  return 1.0f / x;
#endif
}
// gelu tanh-form, rewritten exactly as v * sigmoid(2u):
// 0.5*(1+tanh(u)) == sigmoid(2u)
__device__ __forceinline__ float gelu_tanh(float v){
  float t = v * v;
  float u = fmaf(0.044715f * t, v, v);        // v + 0.044715 v^3
  float z = 1.5957691216057308f * u;          // 2 * 0.7978845608
  float e = __expf(-z);
  return v * rcpf(1.0f + e);
}

__device__ __forceinline__ f32x4 mfma16bf16(short4v a, short4v b, f32x4 c){
#if __has_builtin(__builtin_amdgcn_mfma_f32_16x16x16bf16_1k)
  return __builtin_amdgcn_mfma_f32_16x16x16bf16_1k(a, b, c, 0, 0, 0);
#else
  f32x4 d;
  asm volatile("v_mfma_f32_16x16x16_bf16 %0, %1, %2, %3"
               : "=v"(d) : "v"(a), "v"(b), "v"(c));
  return d;
#endif
}

// ---- pack weights (f32 [M][K]) into bf16 MFMA A-fragment tiles -------------
// qkv/proj/w1: tile (mt,kt): lane l (0..63) elem r: W[mt*16+(l&15)][kt*32+8*(l>>4)+r]
// w2: tile (m,hp): lane l slot s: W2[m*16+(l&15)][hp*32 + pi(l>>4,s)]
//     pi(lg,s) = s<4 ? 4*lg+s : 16+4*lg+(s-4)   (matches W1-D/gelu reg layout)
__global__ __launch_bounds__(256) void k_pack(
    const float* __restrict__ qkvw, const float* __restrict__ projw,
    const float* __restrict__ w1, const float* __restrict__ w2,
    u16* __restrict__ wf)
{
  int tile = blockIdx.x;
  int t = threadIdx.x;
  int l = t >> 1, half = t & 1;
  if (l >= 64) return;
  int lg = l >> 4;
  if (tile >= 256){
    int ti = tile - 256;
    int m = ti >> 4, hp = ti & 15;
    int row = m * 16 + (l & 15);
    u16 o[4];
    #pragma unroll
    for (int j = 0; j < 4; ++j){
      int s = half * 4 + j;
      int kloc = (s < 4) ? (4 * lg + s) : (16 + 4 * lg + (s - 4));
      o[j] = f2bf(w2[(size_t)row * 512 + hp * 32 + kloc]);
    }
    u32x2 v; v[0] = (u32)o[0] | ((u32)o[1] << 16); v[1] = (u32)o[2] | ((u32)o[3] << 16);
    *(u32x2*)(wf + 262144 + ti * 1024 + l * 8 + half * 4) = v;
    return;
  }
  const float* W; int base, ti;
  if (tile < 96)       { W = qkvw; base = 0;      ti = tile; }
  else if (tile < 128) { W = projw; base = 98304;  ti = tile - 96; }
  else                 { W = w1;   base = 131072; ti = tile - 128; }
  int mt = ti / 4, kt = ti % 4;
  int r0 = half * 4;
  int m = mt * 16 + (l & 15);
  int kb = kt * 32 + 8 * lg + r0;
  u16 o[4];
  #pragma unroll
  for (int j = 0; j < 4; ++j) o[j] = f2bf(W[(size_t)m * 128 + kb + j]);
  u32x2 v; v[0] = (u32)o[0] | ((u32)o[1] << 16); v[1] = (u32)o[2] | ((u32)o[3] << 16);
  *(u32x2*)(wf + base + ti * 1024 + l * 8 + r0) = v;
}

// ---- kernel 1: channel-LN + QKV GEMM; q/k/v planes [b][h][pix][32] bf16 ----
// LN stats accumulate in registers during the global load (wave w owns
// channels w*32..w*32+31 for pixel = lane); x never round-trips LDS.
__global__ __launch_bounds__(256, 2) void k_ln_qkv(
    const float* __restrict__ x, const float* __restrict__ n1w,
    const float* __restrict__ n1b, const u16* __restrict__ wfq,
    const float* __restrict__ qkvb, u16* __restrict__ qkvp)
{
  __shared__ __align__(16) char smem[66560];
  // @0: xn B-frag 16 KB; @16384: red[512]f32 / mu[64] / rs[64] (aliased by out-stage)
  float* red  = (float*)(smem + 16384);
  float* mu_s = (float*)(smem + 18432);
  float* rs_s = (float*)(smem + 18688);

  const int t = threadIdx.x;
  const int w = t >> 6, l = t & 63;
  const int P0 = blockIdx.x * 64;
  const int b = P0 >> 16;
  const int pix0 = P0 & 65535;
  const float* xb = x + ((size_t)b * 128) * HW + pix0 + l;

  float xv[32];
  float s = 0.f, s2 = 0.f;
  #pragma unroll
  for (int j = 0; j < 32; ++j){
    float v = xb[(size_t)(w * 32 + j) * HW];
    xv[j] = v; s += v; s2 += v * v;
  }
  red[w * 64 + l] = s;
  red[256 + w * 64 + l] = s2;
  __syncthreads();
  if (t < 64){
    float ss  = red[t] + red[64 + t] + red[128 + t] + red[192 + t];
    float ss2 = red[256 + t] + red[320 + t] + red[384 + t] + red[448 + t];
    float mu = ss * 0.0078125f;
    float var = ss2 * 0.0078125f - mu * mu;
    mu_s[t] = mu; rs_s[t] = rsqrtf(var + 1e-5f);
  }
  __syncthreads();
  {
    float mu = mu_s[l], rs = rs_s[l];
    #pragma unroll
    for (int jj = 0; jj < 4; ++jj){
      int c0 = w * 32 + jj * 8;
      u32x4 pk;
      #pragma unroll
      for (int k2 = 0; k2 < 4; ++k2){
        float v0 = (xv[jj*8 + k2*2    ] - mu) * rs * n1w[c0 + k2*2    ] + n1b[c0 + k2*2    ];
        float v1 = (xv[jj*8 + k2*2 + 1] - mu) * rs * n1w[c0 + k2*2 + 1] + n1b[c0 + k2*2 + 1];
        pk[k2] = pkbf(v0, v1);
      }
      *(u32x4*)(smem + l * 256 + (((w * 4 + jj) ^ (l & 7)) << 4)) = pk;
    }
  }
  __syncthreads();

  const int lg = l >> 4, ln = l & 15;
  const bf16x8* wfrag = (const bf16x8*)wfq;
  f32x4 acc[6][4];
  #pragma unroll
  for (int m = 0; m < 6; ++m)
    #pragma unroll
    for (int n = 0; n < 4; ++n) acc[m][n] = (f32x4)(0.f);
  #pragma unroll
  for (int kt = 0; kt < 4; ++kt){
    bf16x8 a[6], bb[4];
    #pragma unroll
    for (int m = 0; m < 6; ++m) a[m] = wfrag[((w*6 + m)*4 + kt)*128 + l];
    #pragma unroll
    for (int n = 0; n < 4; ++n){
      int p = n * 16 + ln;
      bb[n] = *(const bf16x8*)(smem + p * 256 + ((((kt*4 + lg)) ^ (p & 7)) << 4));
    }
    #pragma unroll
    for (int m = 0; m < 6; ++m)
      #pragma unroll
      for (int n = 0; n < 4; ++n)
        acc[m][n] = __builtin_amdgcn_mfma_f32_16x16x32_bf16(a[m], bb[n], acc[m][n], 0, 0, 0);
  }
  #pragma unroll
  for (int m = 0; m < 6; ++m)
    #pragma unroll
    for (int n = 0; n < 4; ++n){
      int o0 = w * 96 + m * 16 + 4 * lg;
      float qs = (o0 < 128) ? 0.17677669529663687f : 1.0f;
      int p = n * 16 + ln;
      u32x2 v;
      v[0] = pkbf((acc[m][n][0] + qkvb[o0+0]) * qs, (acc[m][n][1] + qkvb[o0+1]) * qs);
      v[1] = pkbf((acc[m][n][2] + qkvb[o0+2]) * qs, (acc[m][n][3] + qkvb[o0+3]) * qs);
      *(u32x2*)(smem + 16384 + p * 784 + o0 * 2) = v;
    }
  __syncthreads();
  for (int i = t; i < 3072; i += 256){
    int p = i / 48, c8 = i - p * 48;
    u32x4 v = *(const u32x4*)(smem + 16384 + p * 784 + c8 * 16);
    int sel = c8 >> 4, hh = (c8 >> 2) & 3, c0 = (c8 & 3) * 8;
    u16* plane = qkvp + (size_t)sel * 67108864ull;
    *(u32x4*)(plane + (((size_t)(b*4 + hh)) * 65536 + pix0 + p) * 32 + c0) = v;
  }
}

// ---- kernel 2: 7x7 local attention via MFMA; writes over the q plane -------
__global__ __launch_bounds__(256, 2) void k_attn(
    u16* qbuf, const u16* __restrict__ kbuf, const u16* __restrict__ vbuf)
{
  __shared__ __align__(16) u16 Klds[4 * 512 * 8];
  __shared__ __align__(16) u16 VT[32 * 532 + 16];
  const int t = threadIdx.x;
  const int blk = blockIdx.x;
  const int tx16 = blk & 15, ty16 = (blk >> 4) & 15;
  const int h = (blk >> 8) & 3, b = blk >> 10;
  const int y0 = ty16 * 16, x0 = tx16 * 16;
  const int bh = b * 4 + h;
  const u16* kg = kbuf + (size_t)bh * 65536 * 32;
  const u16* vg = vbuf + (size_t)bh * 65536 * 32;

  for (int i = t; i < 2130; i += 256) ((u32x4*)VT)[i] = (u32x4){0u,0u,0u,0u};
  __syncthreads();

  for (int pix = t; pix < 484; pix += 256){
    int yy = pix / 22, xx = pix - yy * 22;
    int gy = y0 + yy - 3, gx = x0 + xx - 3;
    bool ok = (gy >= 0 && gy < 256 && gx >= 0 && gx < 256);
    u32x4 kv[4], vv[4];
    #pragma unroll
    for (int j = 0; j < 4; ++j){ kv[j] = (u32x4){0u,0u,0u,0u}; vv[j] = (u32x4){0u,0u,0u,0u}; }
    if (ok){
      size_t gb = ((size_t)(gy * 256 + gx)) * 32;
      #pragma unroll
      for (int j = 0; j < 4; ++j){
        kv[j] = *(const u32x4*)(kg + gb + j * 8);
        vv[j] = *(const u32x4*)(vg + gb + j * 8);
      }
    }
    #pragma unroll
    for (int j = 0; j < 4; ++j)
      *(u32x4*)(Klds + (j * 512 + pix) * 8) = kv[j];
    int vb = yy * 24 + xx;
    #pragma unroll
    for (int j = 0; j < 4; ++j)
      #pragma unroll
      for (int ww = 0; ww < 4; ++ww){
        int c = j * 8 + ww * 2;
        VT[(c    ) * 532 + vb] = (u16)(vv[j][ww] & 0xffffu);
        VT[(c + 1) * 532 + vb] = (u16)(vv[j][ww] >> 16);
      }
  }
  __syncthreads();

  const int l = t & 63, w = t >> 6;
  const int ln = l & 15, g = l >> 4;

  bool mk[2][4];
  #pragma unroll
  for (int sl = 0; sl < 2; ++sl)
    #pragma unroll
    for (int r = 0; r < 4; ++r)
      mk[sl][r] = ((unsigned)(sl * 16 + g * 4 + r - ln)) <= 6u;

  for (int rt = 0; rt < 4; ++rt){
    int yl = rt * 4 + w;
    int qpix = (y0 + yl) * 256 + x0 + ln;
    u16* qp = qbuf + ((size_t)bh * 65536 + qpix) * 32;
    bf16x8 qf = *(const bf16x8*)(qp + g * 8);

    f32x4 S[7][2];
    #pragma unroll
    for (int oi = 0; oi < 7; ++oi){
      int rowb = (yl + oi) * 22;
      #pragma unroll
      for (int sl = 0; sl < 2; ++sl){
        bf16x8 kf = *(const bf16x8*)(Klds + (g * 512 + rowb + sl * 16 + ln) * 8);
        f32x4 z = (f32x4)(0.f);
        S[oi][sl] = __builtin_amdgcn_mfma_f32_16x16x32_bf16(kf, qf, z, 0, 0, 0);
      }
    }
    float m = -3e38f;
    #pragma unroll
    for (int oi = 0; oi < 7; ++oi)
      #pragma unroll
      for (int sl = 0; sl < 2; ++sl)
        #pragma unroll
        for (int r = 0; r < 4; ++r){
          float v = mk[sl][r] ? S[oi][sl][r] : -3e38f;
          S[oi][sl][r] = v;
          m = fmaxf(m, v);
        }
    m = fmaxf(m, __shfl_xor(m, 16));
    m = fmaxf(m, __shfl_xor(m, 32));
    float sum = 0.f;
    #pragma unroll
    for (int oi = 0; oi < 7; ++oi)
      #pragma unroll
      for (int sl = 0; sl < 2; ++sl)
        #pragma unroll
        for (int r = 0; r < 4; ++r){
          float e = __expf(S[oi][sl][r] - m);
          S[oi][sl][r] = e;
          sum += e;
        }
    sum += __shfl_xor(sum, 16);
    sum += __shfl_xor(sum, 32);
    float inv = 1.f / sum;

    short4v P[7][2];
    #pragma unroll
    for (int oi = 0; oi < 7; ++oi)
      #pragma unroll
      for (int sl = 0; sl < 2; ++sl){
        union { u32x2 u; short4v s; } cv;
        cv.u[0] = pkbf(S[oi][sl][0], S[oi][sl][1]);
        cv.u[1] = pkbf(S[oi][sl][2], S[oi][sl][3]);
        P[oi][sl] = cv.s;
      }

    f32x4 O0 = (f32x4)(0.f), O1 = (f32x4)(0.f);
    #pragma unroll
    for (int oi = 0; oi < 7; ++oi){
      int rowE = (yl + oi) * 24;
      #pragma unroll
      for (int sl = 0; sl < 2; ++sl){
        int xb = rowE + sl * 16 + 4 * g;
        short4v v0 = *(const short4v*)(VT + (ln     ) * 532 + xb);
        short4v v1 = *(const short4v*)(VT + (ln + 16) * 532 + xb);
        O0 = mfma16bf16(v0, P[oi][sl], O0);
        O1 = mfma16bf16(v1, P[oi][sl], O1);
      }
    }
    u32x2 o0, o1;
    o0[0] = pkbf(O0[0]*inv, O0[1]*inv);
    o0[1] = pkbf(O0[2]*inv, O0[3]*inv);
    o1[0] = pkbf(O1[0]*inv, O1[1]*inv);
    o1[1] = pkbf(O1[2]*inv, O1[3]*inv);
    *(u32x2*)(qp + 4 * g)      = o0;
    *(u32x2*)(qp + 16 + 4 * g) = o1;
  }
}

// ---- kernel 3: proj + residual + reg-LN2 + register-resident MLP -----------
// Each wave owns 16 pixels (all 128 channels). h never touches LDS:
// W1's MFMA D-layout is directly the B-operand of the pi-packed W2 MFMA.
__global__ __launch_bounds__(256, 3) void k_proj_mlp(
    const u16* __restrict__ ao, const u16* __restrict__ wfp,
    const float* __restrict__ projb, const float* __restrict__ x,
    const float* __restrict__ n2w, const float* __restrict__ n2b,
    const u16* __restrict__ wf1, const float* __restrict__ b1,
    const u16* __restrict__ wf2, const float* __restrict__ b2,
    float* __restrict__ yout)
{
  __shared__ __align__(16) char smem[16384];
  const int t = threadIdx.x;
  const int P0 = blockIdx.x * 64;
  const int b = P0 >> 16;
  const int pix0 = P0 & 65535;

  // stage attention-out tile (fully coalesced: 4 lanes x 16B = one pixel row)
  {
    int p = t >> 2, c4 = t & 3;
    #pragma unroll
    for (int hh = 0; hh < 4; ++hh){
      int ch = hh * 4 + c4;
      u32x4 v = *(const u32x4*)(ao + (((size_t)(b*4 + hh)) * 65536 + pix0 + p) * 32 + c4 * 8);
      *(u32x4*)(smem + p * 256 + ((ch ^ (p & 7)) << 4)) = v;
    }
  }
  __syncthreads();   // the only barrier in this kernel

  const int w = t >> 6, l = t & 63, lg = l >> 4, ln = l & 15;
  const int p = w * 16 + ln;          // this wave's pixel rows: [w*16, w*16+16)
  const int pixg = pix0 + p;

  // B-fragments of attention-out for this wave's pixel column (kept in regs)
  bf16x8 bb[4];
  #pragma unroll
  for (int kt = 0; kt < 4; ++kt)
    bb[kt] = *(const bf16x8*)(smem + p * 256 + (((kt*4 + lg) ^ (p & 7)) << 4));

  // ---- proj GEMM: all 8 out-tiles
  const bf16x8* wfrag = (const bf16x8*)wfp;
  f32x4 yv[8];
  #pragma unroll
  for (int m = 0; m < 8; ++m) yv[m] = (f32x4)(0.f);
  #pragma unroll
  for (int kt = 0; kt < 4; ++kt)
    #pragma unroll
    for (int m = 0; m < 8; ++m){
      bf16x8 a = wfrag[(m*4 + kt)*128 + l];
      yv[m] = __builtin_amdgcn_mfma_f32_16x16x32_bf16(a, bb[kt], yv[m], 0, 0, 0);
    }

  // ---- bias + x residual; LN stats fully in registers (lanes l, l^16, l^32
  // share the same pixel), 2 shfl_xor per moment
  float s = 0.f, s2 = 0.f;
  #pragma unroll
  for (int m = 0; m < 8; ++m){
    int c0 = m * 16 + 4 * lg;
    f32x4 pbv = *(const f32x4*)(projb + c0);
    size_t base = ((size_t)(b * 128 + c0)) * HW + pixg;
    #pragma unroll
    for (int r = 0; r < 4; ++r){
      float val = x[base + (size_t)r * HW] + yv[m][r] + pbv[r];
      yv[m][r] = val;
      s += val; s2 = fmaf(val, val, s2);
    }
  }
  s  += __shfl_xor(s, 16);  s  += __shfl_xor(s, 32);
  s2 += __shfl_xor(s2, 16); s2 += __shfl_xor(s2, 32);
  float mu = s * 0.0078125f;
  float rs = rsqrtf(s2 * 0.0078125f - mu * mu + 1e-5f);

  // ---- normalize from regs into the (wave-local) LDS rows; no barrier needed
  #pragma unroll
  for (int m = 0; m < 8; ++m){
    int c0 = m * 16 + 4 * lg;
    f32x4 wv = *(const f32x4*)(n2w + c0);
    f32x4 bv = *(const f32x4*)(n2b + c0);
    float x0 = (yv[m][0] - mu) * rs * wv[0] + bv[0];
    float x1 = (yv[m][1] - mu) * rs * wv[1] + bv[1];
    float x2 = (yv[m][2] - mu) * rs * wv[2] + bv[2];
    float x3 = (yv[m][3] - mu) * rs * wv[3] + bv[3];
    int g8 = c0 >> 3;                  // 2m + (lg>>1)
    u32x2 pk; pk[0] = pkbf(x0, x1); pk[1] = pkbf(x2, x3);
    *(u32x2*)(smem + p * 256 + ((g8 ^ (p & 7)) << 4) + ((lg & 1) << 3)) = pk;
  }
  // read back xn fragments (same wave-local rows; DS pipe is in-order per wave)
  #pragma unroll
  for (int kt = 0; kt < 4; ++kt)
    bb[kt] = *(const bf16x8*)(smem + p * 256 + (((kt*4 + lg) ^ (p & 7)) << 4));

  // ---- MLP: W1 -> gelu -> W2, h entirely in registers
  const bf16x8* wf1f = (const bf16x8*)wf1;
  const bf16x8* wf2f = (const bf16x8*)wf2;
  f32x4 acc2[8];
  #pragma unroll
  for (int m = 0; m < 8; ++m) acc2[m] = (f32x4)(0.f);

  #pragma unroll 2
  for (int hp = 0; hp < 16; ++hp){
    f32x4 ha = (f32x4)(0.f), hb = (f32x4)(0.f);
    #pragma unroll
    for (int kt = 0; kt < 4; ++kt){
      ha = __builtin_amdgcn_mfma_f32_16x16x32_bf16(wf1f[((2*hp    )*4 + kt)*128 + l], bb[kt], ha, 0, 0, 0);
      hb = __builtin_amdgcn_mfma_f32_16x16x32_bf16(wf1f[((2*hp + 1)*4 + kt)*128 + l], bb[kt], hb, 0, 0, 0);
    }
    f32x4 b1a = *(const f32x4*)(b1 + hp * 32 + 4 * lg);
    f32x4 b1b = *(const f32x4*)(b1 + hp * 32 + 16 + 4 * lg);
    float g0 = gelu_tanh(ha[0] + b1a[0]);
    float g1 = gelu_tanh(ha[1] + b1a[1]);
    float g2 = gelu_tanh(ha[2] + b1a[2]);
    float g3 = gelu_tanh(ha[3] + b1a[3]);
    float g4 = gelu_tanh(hb[0] + b1b[0]);
    float g5 = gelu_tanh(hb[1] + b1b[1]);
    float g6 = gelu_tanh(hb[2] + b1b[2]);
    float g7 = gelu_tanh(hb[3] + b1b[3]);
    union { u32x4 u; bf16x8 h; } hf;
    hf.u[0] = pkbf(g0, g1); hf.u[1] = pkbf(g2, g3);
    hf.u[2] = pkbf(g4, g5); hf.u[3] = pkbf(g6, g7);
    #pragma unroll
    for (int m = 0; m < 8; ++m)
      acc2[m] = __builtin_amdgcn_mfma_f32_16x16x32_bf16(wf2f[(m*16 + hp)*128 + l], hf.h, acc2[m], 0, 0, 0);
  }

  // ---- epilogue: out = y (regs) + mlp + b2
  #pragma unroll
  for (int m = 0; m < 8; ++m){
    int c0 = m * 16 + 4 * lg;
    f32x4 b2v = *(const f32x4*)(b2 + c0);
    size_t base = ((size_t)(b * 128 + c0)) * HW + pixg;
    #pragma unroll
    for (int r = 0; r < 4; ++r)
      yout[base + (size_t)r * HW] = yv[m][r] + acc2[m][r] + b2v[r];
  }
}

extern "C" void kernel_launch(void* const* d_in, const int* in_sizes, int n_in,
                              void* d_out, int out_size, void* d_ws, size_t ws_size,
                              hipStream_t stream)
{
  const float* x    = (const float*)d_in[0];
  const float* n1w  = (const float*)d_in[1];
  const float* n1b  = (const float*)d_in[2];
  const float* qkvw = (const float*)d_in[3];
  const float* qkvb = (const float*)d_in[4];
  const float* pw   = (const float*)d_in[5];
  const float* pb   = (const float*)d_in[6];
  const float* n2w  = (const float*)d_in[7];
  const float* n2b  = (const float*)d_in[8];
  const float* w1   = (const float*)d_in[9];
  const float* b1   = (const float*)d_in[10];
  const float* w2   = (const float*)d_in[11];
  const float* b2   = (const float*)d_in[12];

  u16* qkvp = (u16*)d_ws;                  // q/k/v planes, each [b][4][65536][32] = 128 MB
  u16* qbuf = qkvp;                        // q plane doubles as attention output
  u16* kbuf = qkvp + 67108864ull;
  u16* vbuf = qkvp + 134217728ull;
  u16* wf   = qkvp + 201326592ull;         // packed weights (768 KB)
  u16* wfq = wf;
  u16* wfp = wf + 98304;
  u16* wf1 = wf + 131072;
  u16* wf2 = wf + 262144;
  float* y = (float*)d_out;

  k_pack<<<384, 256, 0, stream>>>(qkvw, pw, w1, w2, wf);
  k_ln_qkv<<<8192, 256, 0, stream>>>(x, n1w, n1b, wfq, qkvb, qkvp);
  k_attn<<<8192, 256, 0, stream>>>(qbuf, kbuf, vbuf);
  k_proj_mlp<<<8192, 256, 0, stream>>>(qbuf, wfp, pb, x, n2w, n2b, wf1, b1, wf2, b2, y);
}

// Round 7
// 733.701 us; speedup vs baseline: 1.6295x; 1.6295x over previous
//
#include <hip/hip_runtime.h>
#include <hip/hip_bf16.h>

typedef unsigned short u16;
typedef unsigned int u32;
typedef __attribute__((ext_vector_type(4))) u32 u32x4;
typedef __attribute__((ext_vector_type(2))) u32 u32x2;
typedef __attribute__((ext_vector_type(8))) __bf16 bf16x8;
typedef __attribute__((ext_vector_type(4))) float f32x4;
typedef __attribute__((ext_vector_type(4))) short short4v;

#define HW 65536

__device__ __forceinline__ u16 f2bf(float f){
  union { u32 i; float f; } v; v.f = f;
  u32 r = v.i + 0x7fffu + ((v.i >> 16) & 1u);
  return (u16)(r >> 16);
}
__device__ __forceinline__ u32 pkbf(float a, float b){
  __bf16 lo = (__bf16)a, hi = (__bf16)b;
  u16 ulo = __builtin_bit_cast(u16, lo);
  u16 uhi = __builtin_bit_cast(u16, hi);
  return (u32)ulo | ((u32)uhi << 16);
}
__device__ __forceinline__ float rcpf(float x){
#if __has_builtin(__builtin_amdgcn_rcpf)
  return __builtin_amdgcn_rcpf(x);
#else
  return 1.0f / x;
#endif
}
__device__ __forceinline__ float gelu_tanh(float v){
  float t = v * v;
  float u = fmaf(0.044715f * t, v, v);
  float z = 1.5957691216057308f * u;
  float e = __expf(-z);
  return v * rcpf(1.0f + e);
}

__device__ __forceinline__ f32x4 mfma16bf16(short4v a, short4v b, f32x4 c){
#if __has_builtin(__builtin_amdgcn_mfma_f32_16x16x16bf16_1k)
  return __builtin_amdgcn_mfma_f32_16x16x16bf16_1k(a, b, c, 0, 0, 0);
#else
  f32x4 d;
  asm volatile("v_mfma_f32_16x16x16_bf16 %0, %1, %2, %3"
               : "=v"(d) : "v"(a), "v"(b), "v"(c));
  return d;
#endif
}

// ---- pack weights into DENSE (1KB) bf16 MFMA A-fragment tiles --------------
// qkv/proj/w1 tile (mt,kt): lane l elem r: W[mt*16+(l&15)][kt*32+8*(l>>4)+r]
// w2 tile ti=hp*8+m: lane l slot s: W2[m*16+(l&15)][hp*32 + pi(l>>4,s)]
//   pi(lg,s) = s<4 ? 4*lg+s : 16+4*lg+(s-4)
// u16 bases: qkv 0 (96 tiles), proj 49152 (32), w1 65536 (128), w2 131072 (128)
__global__ __launch_bounds__(256) void k_pack(
    const float* __restrict__ qkvw, const float* __restrict__ projw,
    const float* __restrict__ w1, const float* __restrict__ w2,
    u16* __restrict__ wf)
{
  int tile = blockIdx.x;
  int t = threadIdx.x;
  int l = t >> 1, half = t & 1;
  if (l >= 64) return;
  int lg = l >> 4;
  if (tile >= 256){
    int ti = tile - 256;
    int hp = ti >> 3, m = ti & 7;
    int row = m * 16 + (l & 15);
    u16 o[4];
    #pragma unroll
    for (int j = 0; j < 4; ++j){
      int s = half * 4 + j;
      int kloc = (s < 4) ? (4 * lg + s) : (16 + 4 * lg + (s - 4));
      o[j] = f2bf(w2[(size_t)row * 512 + hp * 32 + kloc]);
    }
    u32x2 v; v[0] = (u32)o[0] | ((u32)o[1] << 16); v[1] = (u32)o[2] | ((u32)o[3] << 16);
    *(u32x2*)(wf + 131072 + ti * 512 + l * 8 + half * 4) = v;
    return;
  }
  const float* W; int base, ti;
  if (tile < 96)       { W = qkvw; base = 0;     ti = tile; }
  else if (tile < 128) { W = projw; base = 49152; ti = tile - 96; }
  else                 { W = w1;   base = 65536; ti = tile - 128; }
  int mt = ti / 4, kt = ti % 4;
  int r0 = half * 4;
  int m = mt * 16 + (l & 15);
  int kb = kt * 32 + 8 * lg + r0;
  u16 o[4];
  #pragma unroll
  for (int j = 0; j < 4; ++j) o[j] = f2bf(W[(size_t)m * 128 + kb + j]);
  u32x2 v; v[0] = (u32)o[0] | ((u32)o[1] << 16); v[1] = (u32)o[2] | ((u32)o[3] << 16);
  *(u32x2*)(wf + base + ti * 512 + l * 8 + r0) = v;
}

// ---- kernel 1: channel-LN + QKV GEMM; q/k/v planes [b][h][pix][32] bf16 ----
__global__ __launch_bounds__(256, 2) void k_ln_qkv(
    const float* __restrict__ x, const float* __restrict__ n1w,
    const float* __restrict__ n1b, const u16* __restrict__ wfq,
    const float* __restrict__ qkvb, u16* __restrict__ qkvp)
{
  __shared__ __align__(16) char smem[66560];
  float* red  = (float*)(smem + 16384);
  float* mu_s = (float*)(smem + 18432);
  float* rs_s = (float*)(smem + 18688);

  const int t = threadIdx.x;
  const int w = t >> 6, l = t & 63;
  const int P0 = blockIdx.x * 64;
  const int b = P0 >> 16;
  const int pix0 = P0 & 65535;
  const float* xb = x + ((size_t)b * 128) * HW + pix0 + l;

  float xv[32];
  float s = 0.f, s2 = 0.f;
  #pragma unroll
  for (int j = 0; j < 32; ++j){
    float v = xb[(size_t)(w * 32 + j) * HW];
    xv[j] = v; s += v; s2 += v * v;
  }
  red[w * 64 + l] = s;
  red[256 + w * 64 + l] = s2;
  __syncthreads();
  if (t < 64){
    float ss  = red[t] + red[64 + t] + red[128 + t] + red[192 + t];
    float ss2 = red[256 + t] + red[320 + t] + red[384 + t] + red[448 + t];
    float mu = ss * 0.0078125f;
    float var = ss2 * 0.0078125f - mu * mu;
    mu_s[t] = mu; rs_s[t] = rsqrtf(var + 1e-5f);
  }
  __syncthreads();
  {
    float mu = mu_s[l], rs = rs_s[l];
    #pragma unroll
    for (int jj = 0; jj < 4; ++jj){
      int c0 = w * 32 + jj * 8;
      u32x4 pk;
      #pragma unroll
      for (int k2 = 0; k2 < 4; ++k2){
        float v0 = (xv[jj*8 + k2*2    ] - mu) * rs * n1w[c0 + k2*2    ] + n1b[c0 + k2*2    ];
        float v1 = (xv[jj*8 + k2*2 + 1] - mu) * rs * n1w[c0 + k2*2 + 1] + n1b[c0 + k2*2 + 1];
        pk[k2] = pkbf(v0, v1);
      }
      *(u32x4*)(smem + l * 256 + (((w * 4 + jj) ^ (l & 7)) << 4)) = pk;
    }
  }
  __syncthreads();

  const int lg = l >> 4, ln = l & 15;
  const bf16x8* wfrag = (const bf16x8*)wfq;
  f32x4 acc[6][4];
  #pragma unroll
  for (int m = 0; m < 6; ++m)
    #pragma unroll
    for (int n = 0; n < 4; ++n) acc[m][n] = (f32x4)(0.f);
  #pragma unroll
  for (int kt = 0; kt < 4; ++kt){
    bf16x8 a[6], bb[4];
    #pragma unroll
    for (int m = 0; m < 6; ++m) a[m] = wfrag[((w*6 + m)*4 + kt)*64 + l];
    #pragma unroll
    for (int n = 0; n < 4; ++n){
      int p = n * 16 + ln;
      bb[n] = *(const bf16x8*)(smem + p * 256 + ((((kt*4 + lg)) ^ (p & 7)) << 4));
    }
    #pragma unroll
    for (int m = 0; m < 6; ++m)
      #pragma unroll
      for (int n = 0; n < 4; ++n)
        acc[m][n] = __builtin_amdgcn_mfma_f32_16x16x32_bf16(a[m], bb[n], acc[m][n], 0, 0, 0);
  }
  #pragma unroll
  for (int m = 0; m < 6; ++m)
    #pragma unroll
    for (int n = 0; n < 4; ++n){
      int o0 = w * 96 + m * 16 + 4 * lg;
      float qs = (o0 < 128) ? 0.17677669529663687f : 1.0f;
      int p = n * 16 + ln;
      u32x2 v;
      v[0] = pkbf((acc[m][n][0] + qkvb[o0+0]) * qs, (acc[m][n][1] + qkvb[o0+1]) * qs);
      v[1] = pkbf((acc[m][n][2] + qkvb[o0+2]) * qs, (acc[m][n][3] + qkvb[o0+3]) * qs);
      *(u32x2*)(smem + 16384 + p * 784 + o0 * 2) = v;
    }
  __syncthreads();
  for (int i = t; i < 3072; i += 256){
    int p = i / 48, c8 = i - p * 48;
    u32x4 v = *(const u32x4*)(smem + 16384 + p * 784 + c8 * 16);
    int sel = c8 >> 4, hh = (c8 >> 2) & 3, c0 = (c8 & 3) * 8;
    u16* plane = qkvp + (size_t)sel * 67108864ull;
    *(u32x4*)(plane + (((size_t)(b*4 + hh)) * 65536 + pix0 + p) * 32 + c0) = v;
  }
}

// ---- kernel 2: 7x7 local attention via MFMA; writes over the q plane -------
__global__ __launch_bounds__(256, 2) void k_attn(
    u16* qbuf, const u16* __restrict__ kbuf, const u16* __restrict__ vbuf)
{
  __shared__ __align__(16) u16 Klds[4 * 512 * 8];
  __shared__ __align__(16) u16 VT[32 * 532 + 16];
  const int t = threadIdx.x;
  const int blk = blockIdx.x;
  const int tx16 = blk & 15, ty16 = (blk >> 4) & 15;
  const int h = (blk >> 8) & 3, b = blk >> 10;
  const int y0 = ty16 * 16, x0 = tx16 * 16;
  const int bh = b * 4 + h;
  const u16* kg = kbuf + (size_t)bh * 65536 * 32;
  const u16* vg = vbuf + (size_t)bh * 65536 * 32;

  for (int i = t; i < 2130; i += 256) ((u32x4*)VT)[i] = (u32x4){0u,0u,0u,0u};
  __syncthreads();

  for (int pix = t; pix < 484; pix += 256){
    int yy = pix / 22, xx = pix - yy * 22;
    int gy = y0 + yy - 3, gx = x0 + xx - 3;
    bool ok = (gy >= 0 && gy < 256 && gx >= 0 && gx < 256);
    u32x4 kv[4], vv[4];
    #pragma unroll
    for (int j = 0; j < 4; ++j){ kv[j] = (u32x4){0u,0u,0u,0u}; vv[j] = (u32x4){0u,0u,0u,0u}; }
    if (ok){
      size_t gb = ((size_t)(gy * 256 + gx)) * 32;
      #pragma unroll
      for (int j = 0; j < 4; ++j){
        kv[j] = *(const u32x4*)(kg + gb + j * 8);
        vv[j] = *(const u32x4*)(vg + gb + j * 8);
      }
    }
    #pragma unroll
    for (int j = 0; j < 4; ++j)
      *(u32x4*)(Klds + (j * 512 + pix) * 8) = kv[j];
    int vb = yy * 24 + xx;
    #pragma unroll
    for (int j = 0; j < 4; ++j)
      #pragma unroll
      for (int ww = 0; ww < 4; ++ww){
        int c = j * 8 + ww * 2;
        VT[(c    ) * 532 + vb] = (u16)(vv[j][ww] & 0xffffu);
        VT[(c + 1) * 532 + vb] = (u16)(vv[j][ww] >> 16);
      }
  }
  __syncthreads();

  const int l = t & 63, w = t >> 6;
  const int ln = l & 15, g = l >> 4;

  bool mk[2][4];
  #pragma unroll
  for (int sl = 0; sl < 2; ++sl)
    #pragma unroll
    for (int r = 0; r < 4; ++r)
      mk[sl][r] = ((unsigned)(sl * 16 + g * 4 + r - ln)) <= 6u;

  for (int rt = 0; rt < 4; ++rt){
    int yl = rt * 4 + w;
    int qpix = (y0 + yl) * 256 + x0 + ln;
    u16* qp = qbuf + ((size_t)bh * 65536 + qpix) * 32;
    bf16x8 qf = *(const bf16x8*)(qp + g * 8);

    f32x4 S[7][2];
    #pragma unroll
    for (int oi = 0; oi < 7; ++oi){
      int rowb = (yl + oi) * 22;
      #pragma unroll
      for (int sl = 0; sl < 2; ++sl){
        bf16x8 kf = *(const bf16x8*)(Klds + (g * 512 + rowb + sl * 16 + ln) * 8);
        f32x4 z = (f32x4)(0.f);
        S[oi][sl] = __builtin_amdgcn_mfma_f32_16x16x32_bf16(kf, qf, z, 0, 0, 0);
      }
    }
    float m = -3e38f;
    #pragma unroll
    for (int oi = 0; oi < 7; ++oi)
      #pragma unroll
      for (int sl = 0; sl < 2; ++sl)
        #pragma unroll
        for (int r = 0; r < 4; ++r){
          float v = mk[sl][r] ? S[oi][sl][r] : -3e38f;
          S[oi][sl][r] = v;
          m = fmaxf(m, v);
        }
    m = fmaxf(m, __shfl_xor(m, 16));
    m = fmaxf(m, __shfl_xor(m, 32));
    float sum = 0.f;
    #pragma unroll
    for (int oi = 0; oi < 7; ++oi)
      #pragma unroll
      for (int sl = 0; sl < 2; ++sl)
        #pragma unroll
        for (int r = 0; r < 4; ++r){
          float e = __expf(S[oi][sl][r] - m);
          S[oi][sl][r] = e;
          sum += e;
        }
    sum += __shfl_xor(sum, 16);
    sum += __shfl_xor(sum, 32);
    float inv = 1.f / sum;

    short4v P[7][2];
    #pragma unroll
    for (int oi = 0; oi < 7; ++oi)
      #pragma unroll
      for (int sl = 0; sl < 2; ++sl){
        union { u32x2 u; short4v s; } cv;
        cv.u[0] = pkbf(S[oi][sl][0], S[oi][sl][1]);
        cv.u[1] = pkbf(S[oi][sl][2], S[oi][sl][3]);
        P[oi][sl] = cv.s;
      }

    f32x4 O0 = (f32x4)(0.f), O1 = (f32x4)(0.f);
    #pragma unroll
    for (int oi = 0; oi < 7; ++oi){
      int rowE = (yl + oi) * 24;
      #pragma unroll
      for (int sl = 0; sl < 2; ++sl){
        int xb = rowE + sl * 16 + 4 * g;
        short4v v0 = *(const short4v*)(VT + (ln     ) * 532 + xb);
        short4v v1 = *(const short4v*)(VT + (ln + 16) * 532 + xb);
        O0 = mfma16bf16(v0, P[oi][sl], O0);
        O1 = mfma16bf16(v1, P[oi][sl], O1);
      }
    }
    u32x2 o0, o1;
    o0[0] = pkbf(O0[0]*inv, O0[1]*inv);
    o0[1] = pkbf(O0[2]*inv, O0[3]*inv);
    o1[0] = pkbf(O1[0]*inv, O1[1]*inv);
    o1[1] = pkbf(O1[2]*inv, O1[3]*inv);
    *(u32x2*)(qp + 4 * g)      = o0;
    *(u32x2*)(qp + 16 + 4 * g) = o1;
  }
}

// ---- kernel 3: proj + residual + reg-LN2 + reg-h MLP, LDS-staged weights ---
// Waves split pixels (16 each). Weights staged once per block into LDS via
// global_load_lds, double-buffered 32KB chunks (proj, then 8 W1/W2 chunks).
__global__ __launch_bounds__(256, 2) void k_proj_mlp(
    const u16* __restrict__ ao, const u16* __restrict__ wfp,
    const float* __restrict__ projb, const float* __restrict__ x,
    const float* __restrict__ n2w, const float* __restrict__ n2b,
    const u16* __restrict__ wf1, const float* __restrict__ b1,
    const u16* __restrict__ wf2, const float* __restrict__ b2,
    float* __restrict__ yout)
{
  __shared__ __align__(16) char smem[81920];
  // @0: ao/xn frag (16KB); @16384: wbuf0 (32KB); @49152: wbuf1 (32KB)
  const int t = threadIdx.x;
  const int w = t >> 6, l = t & 63, lg = l >> 4, ln = l & 15;
  const int P0 = blockIdx.x * 64;
  const int b = P0 >> 16;
  const int pix0 = P0 & 65535;

  // stage 16KB (wave w handles its 4KB quarter, 4 x 1KB calls)
  auto stage16k = [&](const u16* gsrc, int ldsoff){
    const char* g = (const char*)gsrc;
    int base = w * 4096;
    #pragma unroll
    for (int i = 0; i < 4; ++i){
      int off = base + i * 1024;
      __builtin_amdgcn_global_load_lds(
        (const __attribute__((address_space(1))) u32*)(g + off + l * 16),
        (__attribute__((address_space(3))) u32*)(smem + ldsoff + off),
        16, 0, 0);
    }
  };

  // stage proj (32KB) into wbuf0
  stage16k(wfp, 16384);
  stage16k(wfp + 8192, 16384 + 16384);
  // stage ao tile into frag layout
  {
    int p4 = t >> 2, c4 = t & 3;
    #pragma unroll
    for (int hh = 0; hh < 4; ++hh){
      int ch = hh * 4 + c4;
      u32x4 v = *(const u32x4*)(ao + (((size_t)(b*4 + hh)) * 65536 + pix0 + p4) * 32 + c4 * 8);
      *(u32x4*)(smem + p4 * 256 + ((ch ^ (p4 & 7)) << 4)) = v;
    }
  }
  __syncthreads();

  const int p = w * 16 + ln;
  const int pixg = pix0 + p;

  bf16x8 bb[4];
  #pragma unroll
  for (int kt = 0; kt < 4; ++kt)
    bb[kt] = *(const bf16x8*)(smem + p * 256 + (((kt*4 + lg) ^ (p & 7)) << 4));

  // issue chunk0 stage into wbuf1 (flies under proj compute)
  stage16k(wf1, 49152);
  stage16k(wf2, 49152 + 16384);

  // prefetch x residual (T14)
  float xr[8][4];
  #pragma unroll
  for (int m = 0; m < 8; ++m){
    int c0 = m * 16 + 4 * lg;
    size_t base = ((size_t)(b * 128 + c0)) * HW + pixg;
    #pragma unroll
    for (int r = 0; r < 4; ++r) xr[m][r] = x[base + (size_t)r * HW];
  }

  // ---- proj GEMM from LDS-staged weights
  f32x4 yv[8];
  #pragma unroll
  for (int m = 0; m < 8; ++m) yv[m] = (f32x4)(0.f);
  #pragma unroll
  for (int kt = 0; kt < 4; ++kt)
    #pragma unroll
    for (int m = 0; m < 8; ++m){
      bf16x8 a = *(const bf16x8*)(smem + 16384 + ((m*4 + kt) << 10) + l * 16);
      yv[m] = __builtin_amdgcn_mfma_f32_16x16x32_bf16(a, bb[kt], yv[m], 0, 0, 0);
    }

  // ---- bias + residual; LN stats in registers (2 shfl_xor)
  float s = 0.f, s2 = 0.f;
  #pragma unroll
  for (int m = 0; m < 8; ++m){
    int c0 = m * 16 + 4 * lg;
    f32x4 pbv = *(const f32x4*)(projb + c0);
    #pragma unroll
    for (int r = 0; r < 4; ++r){
      float val = xr[m][r] + yv[m][r] + pbv[r];
      yv[m][r] = val;
      s += val; s2 = fmaf(val, val, s2);
    }
  }
  s  += __shfl_xor(s, 16);  s  += __shfl_xor(s, 32);
  s2 += __shfl_xor(s2, 16); s2 += __shfl_xor(s2, 32);
  float mu = s * 0.0078125f;
  float rs = rsqrtf(s2 * 0.0078125f - mu * mu + 1e-5f);

  // ---- normalize from regs into wave-local LDS rows (no barrier needed)
  #pragma unroll
  for (int m = 0; m < 8; ++m){
    int c0 = m * 16 + 4 * lg;
    f32x4 wv = *(const f32x4*)(n2w + c0);
    f32x4 bv = *(const f32x4*)(n2b + c0);
    float x0 = (yv[m][0] - mu) * rs * wv[0] + bv[0];
    float x1 = (yv[m][1] - mu) * rs * wv[1] + bv[1];
    float x2 = (yv[m][2] - mu) * rs * wv[2] + bv[2];
    float x3 = (yv[m][3] - mu) * rs * wv[3] + bv[3];
    int g8 = c0 >> 3;
    u32x2 pk; pk[0] = pkbf(x0, x1); pk[1] = pkbf(x2, x3);
    *(u32x2*)(smem + p * 256 + ((g8 ^ (p & 7)) << 4) + ((lg & 1) << 3)) = pk;
  }
  #pragma unroll
  for (int kt = 0; kt < 4; ++kt)
    bb[kt] = *(const bf16x8*)(smem + p * 256 + (((kt*4 + lg) ^ (p & 7)) << 4));

  __syncthreads();   // chunk0 staged & everyone done with proj buffer

  // ---- MLP: 8 chunks of 64 hidden rows, double-buffered weights
  f32x4 acc2[8];
  #pragma unroll
  for (int m = 0; m < 8; ++m) acc2[m] = (f32x4)(0.f);

  for (int c = 0; c < 8; ++c){
    const int cur = (c + 1) & 1;              // chunk c lives in wbuf[cur]
    const int curoff = 16384 + (cur << 15);
    if (c < 7){
      const int nxtoff = 16384 + ((cur ^ 1) << 15);
      stage16k(wf1 + (c + 1) * 8192, nxtoff);
      stage16k(wf2 + (c + 1) * 8192, nxtoff + 16384);
    }
    // W1: both hp halves (independent MFMA streams)
    f32x4 h0a = (f32x4)(0.f), h0b = (f32x4)(0.f);
    f32x4 h1a = (f32x4)(0.f), h1b = (f32x4)(0.f);
    #pragma unroll
    for (int kt = 0; kt < 4; ++kt){
      bf16x8 a0 = *(const bf16x8*)(smem + curoff + ((0*4 + kt) << 10) + l * 16);
      bf16x8 a1 = *(const bf16x8*)(smem + curoff + ((1*4 + kt) << 10) + l * 16);
      bf16x8 a2 = *(const bf16x8*)(smem + curoff + ((2*4 + kt) << 10) + l * 16);
      bf16x8 a3 = *(const bf16x8*)(smem + curoff + ((3*4 + kt) << 10) + l * 16);
      h0a = __builtin_amdgcn_mfma_f32_16x16x32_bf16(a0, bb[kt], h0a, 0, 0, 0);
      h0b = __builtin_amdgcn_mfma_f32_16x16x32_bf16(a1, bb[kt], h0b, 0, 0, 0);
      h1a = __builtin_amdgcn_mfma_f32_16x16x32_bf16(a2, bb[kt], h1a, 0, 0, 0);
      h1b = __builtin_amdgcn_mfma_f32_16x16x32_bf16(a3, bb[kt], h1b, 0, 0, 0);
    }
    // gelu + pi-pack (hp = 2c + hpl)
    bf16x8 hf0, hf1;
    {
      int hp0 = 2 * c;
      f32x4 b1a = *(const f32x4*)(b1 + hp0 * 32 + 4 * lg);
      f32x4 b1b = *(const f32x4*)(b1 + hp0 * 32 + 16 + 4 * lg);
      union { u32x4 u; bf16x8 h; } hf;
      hf.u[0] = pkbf(gelu_tanh(h0a[0] + b1a[0]), gelu_tanh(h0a[1] + b1a[1]));
      hf.u[1] = pkbf(gelu_tanh(h0a[2] + b1a[2]), gelu_tanh(h0a[3] + b1a[3]));
      hf.u[2] = pkbf(gelu_tanh(h0b[0] + b1b[0]), gelu_tanh(h0b[1] + b1b[1]));
      hf.u[3] = pkbf(gelu_tanh(h0b[2] + b1b[2]), gelu_tanh(h0b[3] + b1b[3]));
      hf0 = hf.h;
      int hp1 = 2 * c + 1;
      f32x4 c1a = *(const f32x4*)(b1 + hp1 * 32 + 4 * lg);
      f32x4 c1b = *(const f32x4*)(b1 + hp1 * 32 + 16 + 4 * lg);
      hf.u[0] = pkbf(gelu_tanh(h1a[0] + c1a[0]), gelu_tanh(h1a[1] + c1a[1]));
      hf.u[1] = pkbf(gelu_tanh(h1a[2] + c1a[2]), gelu_tanh(h1a[3] + c1a[3]));
      hf.u[2] = pkbf(gelu_tanh(h1b[0] + c1b[0]), gelu_tanh(h1b[1] + c1b[1]));
      hf.u[3] = pkbf(gelu_tanh(h1b[2] + c1b[2]), gelu_tanh(h1b[3] + c1b[3]));
      hf1 = hf.h;
    }
    // W2: 16 tiles from LDS
    #pragma unroll
    for (int m = 0; m < 8; ++m){
      bf16x8 a0 = *(const bf16x8*)(smem + curoff + 16384 + ((0*8 + m) << 10) + l * 16);
      acc2[m] = __builtin_amdgcn_mfma_f32_16x16x32_bf16(a0, hf0, acc2[m], 0, 0, 0);
      bf16x8 a1 = *(const bf16x8*)(smem + curoff + 16384 + ((1*8 + m) << 10) + l * 16);
      acc2[m] = __builtin_amdgcn_mfma_f32_16x16x32_bf16(a1, hf1, acc2[m], 0, 0, 0);
    }
    if (c < 7) __syncthreads();
  }

  // ---- epilogue: out = y (regs) + mlp + b2
  #pragma unroll
  for (int m = 0; m < 8; ++m){
    int c0 = m * 16 + 4 * lg;
    f32x4 b2v = *(const f32x4*)(b2 + c0);
    size_t base = ((size_t)(b * 128 + c0)) * HW + pixg;
    #pragma unroll
    for (int r = 0; r < 4; ++r)
      yout[base + (size_t)r * HW] = yv[m][r] + acc2[m][r] + b2v[r];
  }
}

extern "C" void kernel_launch(void* const* d_in, const int* in_sizes, int n_in,
                              void* d_out, int out_size, void* d_ws, size_t ws_size,
                              hipStream_t stream)
{
  const float* x    = (const float*)d_in[0];
  const float* n1w  = (const float*)d_in[1];
  const float* n1b  = (const float*)d_in[2];
  const float* qkvw = (const float*)d_in[3];
  const float* qkvb = (const float*)d_in[4];
  const float* pw   = (const float*)d_in[5];
  const float* pb   = (const float*)d_in[6];
  const float* n2w  = (const float*)d_in[7];
  const float* n2b  = (const float*)d_in[8];
  const float* w1   = (const float*)d_in[9];
  const float* b1   = (const float*)d_in[10];
  const float* w2   = (const float*)d_in[11];
  const float* b2   = (const float*)d_in[12];

  u16* qkvp = (u16*)d_ws;                  // q/k/v planes, each [b][4][65536][32] = 128 MB
  u16* qbuf = qkvp;                        // q plane doubles as attention output
  u16* kbuf = qkvp + 67108864ull;
  u16* vbuf = qkvp + 134217728ull;
  u16* wf   = qkvp + 201326592ull;         // packed dense weights (384 KB)
  u16* wfq = wf;
  u16* wfp = wf + 49152;
  u16* wf1 = wf + 65536;
  u16* wf2 = wf + 131072;
  float* y = (float*)d_out;

  k_pack<<<384, 256, 0, stream>>>(qkvw, pw, w1, w2, wf);
  k_ln_qkv<<<8192, 256, 0, stream>>>(x, n1w, n1b, wfq, qkvb, qkvp);
  k_attn<<<8192, 256, 0, stream>>>(qbuf, kbuf, vbuf);
  k_proj_mlp<<<8192, 256, 0, stream>>>(qbuf, wfp, pb, x, n2w, n2b, wf1, b1, wf2, b2, y);
}

// Round 8
// 685.366 us; speedup vs baseline: 1.7445x; 1.0705x over previous
//
#include <hip/hip_runtime.h>
#include <hip/hip_bf16.h>

typedef unsigned short u16;
typedef unsigned int u32;
typedef __attribute__((ext_vector_type(4))) u32 u32x4;
typedef __attribute__((ext_vector_type(2))) u32 u32x2;
typedef __attribute__((ext_vector_type(8))) __bf16 bf16x8;
typedef __attribute__((ext_vector_type(4))) float f32x4;
typedef __attribute__((ext_vector_type(4))) short short4v;

#define HW 65536
#define MFMA32(a, b, c) __builtin_amdgcn_mfma_f32_16x16x32_bf16((a), (b), (c), 0, 0, 0)

__device__ __forceinline__ u16 f2bf(float f){
  union { u32 i; float f; } v; v.f = f;
  u32 r = v.i + 0x7fffu + ((v.i >> 16) & 1u);
  return (u16)(r >> 16);
}
__device__ __forceinline__ u32 pkbf(float a, float b){
  __bf16 lo = (__bf16)a, hi = (__bf16)b;
  u16 ulo = __builtin_bit_cast(u16, lo);
  u16 uhi = __builtin_bit_cast(u16, hi);
  return (u32)ulo | ((u32)uhi << 16);
}
__device__ __forceinline__ float rcpf(float x){
#if __has_builtin(__builtin_amdgcn_rcpf)
  return __builtin_amdgcn_rcpf(x);
#else
  return 1.0f / x;
#endif
}
__device__ __forceinline__ float gelu_tanh(float v){
  float t = v * v;
  float u = fmaf(0.044715f * t, v, v);
  float z = 1.5957691216057308f * u;
  float e = __expf(-z);
  return v * rcpf(1.0f + e);
}

__device__ __forceinline__ f32x4 mfma16bf16(short4v a, short4v b, f32x4 c){
#if __has_builtin(__builtin_amdgcn_mfma_f32_16x16x16bf16_1k)
  return __builtin_amdgcn_mfma_f32_16x16x16bf16_1k(a, b, c, 0, 0, 0);
#else
  f32x4 d;
  asm volatile("v_mfma_f32_16x16x16_bf16 %0, %1, %2, %3"
               : "=v"(d) : "v"(a), "v"(b), "v"(c));
  return d;
#endif
}

// ---- pack weights into DENSE (1KB) bf16 MFMA A-fragment tiles --------------
// qkv/proj/w1 tile (mt,kt): lane l elem r: W[mt*16+(l&15)][kt*32+8*(l>>4)+r]
// w2 tile ti=hp*8+m: lane l slot s: W2[m*16+(l&15)][hp*32 + pi(l>>4,s)]
//   pi(lg,s) = s<4 ? 4*lg+s : 16+4*lg+(s-4)
// u16 bases: qkv 0 (96 tiles), proj 49152 (32), w1 65536 (128), w2 131072 (128)
__global__ __launch_bounds__(256) void k_pack(
    const float* __restrict__ qkvw, const float* __restrict__ projw,
    const float* __restrict__ w1, const float* __restrict__ w2,
    u16* __restrict__ wf)
{
  int tile = blockIdx.x;
  int t = threadIdx.x;
  int l = t >> 1, half = t & 1;
  if (l >= 64) return;
  int lg = l >> 4;
  if (tile >= 256){
    int ti = tile - 256;
    int hp = ti >> 3, m = ti & 7;
    int row = m * 16 + (l & 15);
    u16 o[4];
    #pragma unroll
    for (int j = 0; j < 4; ++j){
      int s = half * 4 + j;
      int kloc = (s < 4) ? (4 * lg + s) : (16 + 4 * lg + (s - 4));
      o[j] = f2bf(w2[(size_t)row * 512 + hp * 32 + kloc]);
    }
    u32x2 v; v[0] = (u32)o[0] | ((u32)o[1] << 16); v[1] = (u32)o[2] | ((u32)o[3] << 16);
    *(u32x2*)(wf + 131072 + ti * 512 + l * 8 + half * 4) = v;
    return;
  }
  const float* W; int base, ti;
  if (tile < 96)       { W = qkvw; base = 0;     ti = tile; }
  else if (tile < 128) { W = projw; base = 49152; ti = tile - 96; }
  else                 { W = w1;   base = 65536; ti = tile - 128; }
  int mt = ti / 4, kt = ti % 4;
  int r0 = half * 4;
  int m = mt * 16 + (l & 15);
  int kb = kt * 32 + 8 * lg + r0;
  u16 o[4];
  #pragma unroll
  for (int j = 0; j < 4; ++j) o[j] = f2bf(W[(size_t)m * 128 + kb + j]);
  u32x2 v; v[0] = (u32)o[0] | ((u32)o[1] << 16); v[1] = (u32)o[2] | ((u32)o[3] << 16);
  *(u32x2*)(wf + base + ti * 512 + l * 8 + r0) = v;
}

// ---- kernel 1: channel-LN + QKV GEMM; q/k/v planes [b][h][pix][32] bf16 ----
__global__ __launch_bounds__(256, 2) void k_ln_qkv(
    const float* __restrict__ x, const float* __restrict__ n1w,
    const float* __restrict__ n1b, const u16* __restrict__ wfq,
    const float* __restrict__ qkvb, u16* __restrict__ qkvp)
{
  __shared__ __align__(16) char smem[66560];
  float* red  = (float*)(smem + 16384);
  float* mu_s = (float*)(smem + 18432);
  float* rs_s = (float*)(smem + 18688);

  const int t = threadIdx.x;
  const int w = t >> 6, l = t & 63;
  const int P0 = blockIdx.x * 64;
  const int b = P0 >> 16;
  const int pix0 = P0 & 65535;
  const float* xb = x + ((size_t)b * 128) * HW + pix0 + l;

  float xv[32];
  float s = 0.f, s2 = 0.f;
  #pragma unroll
  for (int j = 0; j < 32; ++j){
    float v = xb[(size_t)(w * 32 + j) * HW];
    xv[j] = v; s += v; s2 += v * v;
  }
  red[w * 64 + l] = s;
  red[256 + w * 64 + l] = s2;
  __syncthreads();
  if (t < 64){
    float ss  = red[t] + red[64 + t] + red[128 + t] + red[192 + t];
    float ss2 = red[256 + t] + red[320 + t] + red[384 + t] + red[448 + t];
    float mu = ss * 0.0078125f;
    float var = ss2 * 0.0078125f - mu * mu;
    mu_s[t] = mu; rs_s[t] = rsqrtf(var + 1e-5f);
  }
  __syncthreads();
  {
    float mu = mu_s[l], rs = rs_s[l];
    #pragma unroll
    for (int jj = 0; jj < 4; ++jj){
      int c0 = w * 32 + jj * 8;
      u32x4 pk;
      #pragma unroll
      for (int k2 = 0; k2 < 4; ++k2){
        float v0 = (xv[jj*8 + k2*2    ] - mu) * rs * n1w[c0 + k2*2    ] + n1b[c0 + k2*2    ];
        float v1 = (xv[jj*8 + k2*2 + 1] - mu) * rs * n1w[c0 + k2*2 + 1] + n1b[c0 + k2*2 + 1];
        pk[k2] = pkbf(v0, v1);
      }
      *(u32x4*)(smem + l * 256 + (((w * 4 + jj) ^ (l & 7)) << 4)) = pk;
    }
  }
  __syncthreads();

  const int lg = l >> 4, ln = l & 15;
  const bf16x8* wfrag = (const bf16x8*)wfq;
  f32x4 acc[6][4];
  #pragma unroll
  for (int m = 0; m < 6; ++m)
    #pragma unroll
    for (int n = 0; n < 4; ++n) acc[m][n] = (f32x4)(0.f);
  #pragma unroll
  for (int kt = 0; kt < 4; ++kt){
    bf16x8 a[6], bb[4];
    #pragma unroll
    for (int m = 0; m < 6; ++m) a[m] = wfrag[((w*6 + m)*4 + kt)*64 + l];
    #pragma unroll
    for (int n = 0; n < 4; ++n){
      int p = n * 16 + ln;
      bb[n] = *(const bf16x8*)(smem + p * 256 + ((((kt*4 + lg)) ^ (p & 7)) << 4));
    }
    #pragma unroll
    for (int m = 0; m < 6; ++m)
      #pragma unroll
      for (int n = 0; n < 4; ++n)
        acc[m][n] = MFMA32(a[m], bb[n], acc[m][n]);
  }
  #pragma unroll
  for (int m = 0; m < 6; ++m)
    #pragma unroll
    for (int n = 0; n < 4; ++n){
      int o0 = w * 96 + m * 16 + 4 * lg;
      float qs = (o0 < 128) ? 0.17677669529663687f : 1.0f;
      int p = n * 16 + ln;
      u32x2 v;
      v[0] = pkbf((acc[m][n][0] + qkvb[o0+0]) * qs, (acc[m][n][1] + qkvb[o0+1]) * qs);
      v[1] = pkbf((acc[m][n][2] + qkvb[o0+2]) * qs, (acc[m][n][3] + qkvb[o0+3]) * qs);
      *(u32x2*)(smem + 16384 + p * 784 + o0 * 2) = v;
    }
  __syncthreads();
  for (int i = t; i < 3072; i += 256){
    int p = i / 48, c8 = i - p * 48;
    u32x4 v = *(const u32x4*)(smem + 16384 + p * 784 + c8 * 16);
    int sel = c8 >> 4, hh = (c8 >> 2) & 3, c0 = (c8 & 3) * 8;
    u16* plane = qkvp + (size_t)sel * 67108864ull;
    *(u32x4*)(plane + (((size_t)(b*4 + hh)) * 65536 + pix0 + p) * 32 + c0) = v;
  }
}

// ---- kernel 2: 7x7 local attention via MFMA; writes over the q plane -------
__global__ __launch_bounds__(256, 2) void k_attn(
    u16* qbuf, const u16* __restrict__ kbuf, const u16* __restrict__ vbuf)
{
  __shared__ __align__(16) u16 Klds[4 * 512 * 8];
  __shared__ __align__(16) u16 VT[32 * 532 + 16];
  const int t = threadIdx.x;
  const int blk = blockIdx.x;
  const int tx16 = blk & 15, ty16 = (blk >> 4) & 15;
  const int h = (blk >> 8) & 3, b = blk >> 10;
  const int y0 = ty16 * 16, x0 = tx16 * 16;
  const int bh = b * 4 + h;
  const u16* kg = kbuf + (size_t)bh * 65536 * 32;
  const u16* vg = vbuf + (size_t)bh * 65536 * 32;

  for (int i = t; i < 2130; i += 256) ((u32x4*)VT)[i] = (u32x4){0u,0u,0u,0u};
  __syncthreads();

  for (int pix = t; pix < 484; pix += 256){
    int yy = pix / 22, xx = pix - yy * 22;
    int gy = y0 + yy - 3, gx = x0 + xx - 3;
    bool ok = (gy >= 0 && gy < 256 && gx >= 0 && gx < 256);
    u32x4 kv[4], vv[4];
    #pragma unroll
    for (int j = 0; j < 4; ++j){ kv[j] = (u32x4){0u,0u,0u,0u}; vv[j] = (u32x4){0u,0u,0u,0u}; }
    if (ok){
      size_t gb = ((size_t)(gy * 256 + gx)) * 32;
      #pragma unroll
      for (int j = 0; j < 4; ++j){
        kv[j] = *(const u32x4*)(kg + gb + j * 8);
        vv[j] = *(const u32x4*)(vg + gb + j * 8);
      }
    }
    #pragma unroll
    for (int j = 0; j < 4; ++j)
      *(u32x4*)(Klds + (j * 512 + pix) * 8) = kv[j];
    int vb = yy * 24 + xx;
    #pragma unroll
    for (int j = 0; j < 4; ++j)
      #pragma unroll
      for (int ww = 0; ww < 4; ++ww){
        int c = j * 8 + ww * 2;
        VT[(c    ) * 532 + vb] = (u16)(vv[j][ww] & 0xffffu);
        VT[(c + 1) * 532 + vb] = (u16)(vv[j][ww] >> 16);
      }
  }
  __syncthreads();

  const int l = t & 63, w = t >> 6;
  const int ln = l & 15, g = l >> 4;

  bool mk[2][4];
  #pragma unroll
  for (int sl = 0; sl < 2; ++sl)
    #pragma unroll
    for (int r = 0; r < 4; ++r)
      mk[sl][r] = ((unsigned)(sl * 16 + g * 4 + r - ln)) <= 6u;

  for (int rt = 0; rt < 4; ++rt){
    int yl = rt * 4 + w;
    int qpix = (y0 + yl) * 256 + x0 + ln;
    u16* qp = qbuf + ((size_t)bh * 65536 + qpix) * 32;
    bf16x8 qf = *(const bf16x8*)(qp + g * 8);

    f32x4 S[7][2];
    #pragma unroll
    for (int oi = 0; oi < 7; ++oi){
      int rowb = (yl + oi) * 22;
      #pragma unroll
      for (int sl = 0; sl < 2; ++sl){
        bf16x8 kf = *(const bf16x8*)(Klds + (g * 512 + rowb + sl * 16 + ln) * 8);
        f32x4 z = (f32x4)(0.f);
        S[oi][sl] = MFMA32(kf, qf, z);
      }
    }
    float m = -3e38f;
    #pragma unroll
    for (int oi = 0; oi < 7; ++oi)
      #pragma unroll
      for (int sl = 0; sl < 2; ++sl)
        #pragma unroll
        for (int r = 0; r < 4; ++r){
          float v = mk[sl][r] ? S[oi][sl][r] : -3e38f;
          S[oi][sl][r] = v;
          m = fmaxf(m, v);
        }
    m = fmaxf(m, __shfl_xor(m, 16));
    m = fmaxf(m, __shfl_xor(m, 32));
    float sum = 0.f;
    #pragma unroll
    for (int oi = 0; oi < 7; ++oi)
      #pragma unroll
      for (int sl = 0; sl < 2; ++sl)
        #pragma unroll
        for (int r = 0; r < 4; ++r){
          float e = __expf(S[oi][sl][r] - m);
          S[oi][sl][r] = e;
          sum += e;
        }
    sum += __shfl_xor(sum, 16);
    sum += __shfl_xor(sum, 32);
    float inv = 1.f / sum;

    short4v P[7][2];
    #pragma unroll
    for (int oi = 0; oi < 7; ++oi)
      #pragma unroll
      for (int sl = 0; sl < 2; ++sl){
        union { u32x2 u; short4v s; } cv;
        cv.u[0] = pkbf(S[oi][sl][0], S[oi][sl][1]);
        cv.u[1] = pkbf(S[oi][sl][2], S[oi][sl][3]);
        P[oi][sl] = cv.s;
      }

    f32x4 O0 = (f32x4)(0.f), O1 = (f32x4)(0.f);
    #pragma unroll
    for (int oi = 0; oi < 7; ++oi){
      int rowE = (yl + oi) * 24;
      #pragma unroll
      for (int sl = 0; sl < 2; ++sl){
        int xb = rowE + sl * 16 + 4 * g;
        short4v v0 = *(const short4v*)(VT + (ln     ) * 532 + xb);
        short4v v1 = *(const short4v*)(VT + (ln + 16) * 532 + xb);
        O0 = mfma16bf16(v0, P[oi][sl], O0);
        O1 = mfma16bf16(v1, P[oi][sl], O1);
      }
    }
    u32x2 o0, o1;
    o0[0] = pkbf(O0[0]*inv, O0[1]*inv);
    o0[1] = pkbf(O0[2]*inv, O0[3]*inv);
    o1[0] = pkbf(O1[0]*inv, O1[1]*inv);
    o1[1] = pkbf(O1[2]*inv, O1[3]*inv);
    *(u32x2*)(qp + 4 * g)      = o0;
    *(u32x2*)(qp + 16 + 4 * g) = o1;
  }
}

// ---- kernel 3: proj + residual + reg-LN2 + reg-h MLP; 128 pixels/block -----
// Each wave owns TWO 16-pixel columns -> every LDS weight read feeds 2 MFMAs.
// LDS 64KB: frag @0 (32KB, dies into chunk buffer), weights @32K (32KB).
__global__ __launch_bounds__(256, 2) void k_proj_mlp(
    const u16* __restrict__ ao, const u16* __restrict__ wfp,
    const float* __restrict__ projb, const float* __restrict__ x,
    const float* __restrict__ n2w, const float* __restrict__ n2b,
    const u16* __restrict__ wf1, const float* __restrict__ b1,
    const u16* __restrict__ wf2, const float* __restrict__ b2,
    float* __restrict__ yout)
{
  __shared__ __align__(16) char smem[65536];
  const int t = threadIdx.x;
  const int w = t >> 6, l = t & 63, lg = l >> 4, ln = l & 15;
  const int P0 = blockIdx.x * 128;
  const int b = P0 >> 16;
  const int pix0 = P0 & 65535;

  auto stage16k = [&](const u16* gsrc, int ldsoff){
    const char* g = (const char*)gsrc;
    int base = w * 4096;
    #pragma unroll
    for (int i = 0; i < 4; ++i){
      int off = base + i * 1024;
      __builtin_amdgcn_global_load_lds(
        (const __attribute__((address_space(1))) u32*)(g + off + l * 16),
        (__attribute__((address_space(3))) u32*)(smem + ldsoff + off),
        16, 0, 0);
    }
  };

  // stage proj weights (32KB) into the high buffer
  stage16k(wfp, 32768);
  stage16k(wfp + 8192, 49152);
  // stage ao (128 pixels x 128 ch) into swizzled frag layout @0
  #pragma unroll
  for (int half = 0; half < 2; ++half){
    int p4 = half * 64 + (t >> 2), c4 = t & 3;
    #pragma unroll
    for (int hh = 0; hh < 4; ++hh){
      int ch = hh * 4 + c4;
      u32x4 v = *(const u32x4*)(ao + (((size_t)(b*4 + hh)) * 65536 + pix0 + p4) * 32 + c4 * 8);
      *(u32x4*)(smem + p4 * 256 + ((ch ^ (p4 & 7)) << 4)) = v;
    }
  }
  __syncthreads();

  const int pA = w * 32 + ln;          // column A pixel row
  const int pB = pA + 16;              // column B

  bf16x8 bbA[4], bbB[4];
  #pragma unroll
  for (int kt = 0; kt < 4; ++kt){
    bbA[kt] = *(const bf16x8*)(smem + pA * 256 + (((kt*4 + lg) ^ (pA & 7)) << 4));
    bbB[kt] = *(const bf16x8*)(smem + pB * 256 + (((kt*4 + lg) ^ (pB & 7)) << 4));
  }

  // ---- proj GEMM (1 weight read -> 2 MFMAs)
  f32x4 yvA[8], yvB[8];
  #pragma unroll
  for (int m = 0; m < 8; ++m){ yvA[m] = (f32x4)(0.f); yvB[m] = (f32x4)(0.f); }
  #pragma unroll
  for (int kt = 0; kt < 4; ++kt)
    #pragma unroll
    for (int m = 0; m < 8; ++m){
      bf16x8 a = *(const bf16x8*)(smem + 32768 + ((m*4 + kt) << 10) + l * 16);
      yvA[m] = MFMA32(a, bbA[kt], yvA[m]);
      yvB[m] = MFMA32(a, bbB[kt], yvB[m]);
    }
  __syncthreads();                 // all proj reads done; buffer reusable
  // stage MLP chunk 0 (flies under residual/LN phase)
  stage16k(wf1, 32768);
  stage16k(wf2, 49152);

  // ---- bias + residual; LN stats in registers (2 shfl per moment per col)
  float sA = 0.f, s2A = 0.f, sB = 0.f, s2B = 0.f;
  #pragma unroll
  for (int m = 0; m < 8; ++m){
    int c0 = m * 16 + 4 * lg;
    f32x4 pbv = *(const f32x4*)(projb + c0);
    size_t baseA = ((size_t)(b * 128 + c0)) * HW + pix0 + pA;
    #pragma unroll
    for (int r = 0; r < 4; ++r){
      float vA = x[baseA + (size_t)r * HW] + yvA[m][r] + pbv[r];
      float vB = x[baseA + 16 + (size_t)r * HW] + yvB[m][r] + pbv[r];
      yvA[m][r] = vA; yvB[m][r] = vB;
      sA += vA; s2A = fmaf(vA, vA, s2A);
      sB += vB; s2B = fmaf(vB, vB, s2B);
    }
  }
  sA  += __shfl_xor(sA, 16);  sA  += __shfl_xor(sA, 32);
  s2A += __shfl_xor(s2A, 16); s2A += __shfl_xor(s2A, 32);
  sB  += __shfl_xor(sB, 16);  sB  += __shfl_xor(sB, 32);
  s2B += __shfl_xor(s2B, 16); s2B += __shfl_xor(s2B, 32);
  float muA = sA * 0.0078125f;
  float rsA = rsqrtf(s2A * 0.0078125f - muA * muA + 1e-5f);
  float muB = sB * 0.0078125f;
  float rsB = rsqrtf(s2B * 0.0078125f - muB * muB + 1e-5f);

  // ---- normalize from regs into wave-local frag rows; read back as B-frags
  #pragma unroll
  for (int m = 0; m < 8; ++m){
    int c0 = m * 16 + 4 * lg;
    f32x4 wv = *(const f32x4*)(n2w + c0);
    f32x4 bv = *(const f32x4*)(n2b + c0);
    int g8 = c0 >> 3;
    u32x2 pkA, pkB;
    pkA[0] = pkbf((yvA[m][0]-muA)*rsA*wv[0]+bv[0], (yvA[m][1]-muA)*rsA*wv[1]+bv[1]);
    pkA[1] = pkbf((yvA[m][2]-muA)*rsA*wv[2]+bv[2], (yvA[m][3]-muA)*rsA*wv[3]+bv[3]);
    pkB[0] = pkbf((yvB[m][0]-muB)*rsB*wv[0]+bv[0], (yvB[m][1]-muB)*rsB*wv[1]+bv[1]);
    pkB[1] = pkbf((yvB[m][2]-muB)*rsB*wv[2]+bv[2], (yvB[m][3]-muB)*rsB*wv[3]+bv[3]);
    *(u32x2*)(smem + pA * 256 + ((g8 ^ (pA & 7)) << 4) + ((lg & 1) << 3)) = pkA;
    *(u32x2*)(smem + pB * 256 + ((g8 ^ (pB & 7)) << 4) + ((lg & 1) << 3)) = pkB;
  }
  #pragma unroll
  for (int kt = 0; kt < 4; ++kt){
    bbA[kt] = *(const bf16x8*)(smem + pA * 256 + (((kt*4 + lg) ^ (pA & 7)) << 4));
    bbB[kt] = *(const bf16x8*)(smem + pB * 256 + (((kt*4 + lg) ^ (pB & 7)) << 4));
  }
  __syncthreads();                 // xn phase done; chunk 0 landed

  // ---- MLP: 8 chunks of 64 hidden rows; buffers ping-pong @32K / @0
  f32x4 acA[8], acB[8];
  #pragma unroll
  for (int m = 0; m < 8; ++m){ acA[m] = (f32x4)(0.f); acB[m] = (f32x4)(0.f); }

  for (int c = 0; c < 8; ++c){
    const int curoff = (c & 1) ? 0 : 32768;
    if (c < 7){
      const int nxt = curoff ^ 32768;
      stage16k(wf1 + (c + 1) * 8192, nxt);
      stage16k(wf2 + (c + 1) * 8192, nxt + 16384);
    }
    // W1: 16 tiles (4 mt x 4 kt); 1 read -> 2 MFMAs
    f32x4 hA[4], hB[4];
    #pragma unroll
    for (int mt = 0; mt < 4; ++mt){ hA[mt] = (f32x4)(0.f); hB[mt] = (f32x4)(0.f); }
    #pragma unroll
    for (int kt = 0; kt < 4; ++kt)
      #pragma unroll
      for (int mt = 0; mt < 4; ++mt){
        bf16x8 a = *(const bf16x8*)(smem + curoff + ((mt*4 + kt) << 10) + l * 16);
        hA[mt] = MFMA32(a, bbA[kt], hA[mt]);
        hB[mt] = MFMA32(a, bbB[kt], hB[mt]);
      }
    // gelu + pi-pack
    int hb0 = c * 64 + 4 * lg;
    f32x4 b1v[4];
    #pragma unroll
    for (int mt = 0; mt < 4; ++mt) b1v[mt] = *(const f32x4*)(b1 + hb0 + mt * 16);
    bf16x8 hfA0, hfA1, hfB0, hfB1;
    {
      union { u32x4 u; bf16x8 h; } uu;
      uu.u[0] = pkbf(gelu_tanh(hA[0][0]+b1v[0][0]), gelu_tanh(hA[0][1]+b1v[0][1]));
      uu.u[1] = pkbf(gelu_tanh(hA[0][2]+b1v[0][2]), gelu_tanh(hA[0][3]+b1v[0][3]));
      uu.u[2] = pkbf(gelu_tanh(hA[1][0]+b1v[1][0]), gelu_tanh(hA[1][1]+b1v[1][1]));
      uu.u[3] = pkbf(gelu_tanh(hA[1][2]+b1v[1][2]), gelu_tanh(hA[1][3]+b1v[1][3]));
      hfA0 = uu.h;
      uu.u[0] = pkbf(gelu_tanh(hA[2][0]+b1v[2][0]), gelu_tanh(hA[2][1]+b1v[2][1]));
      uu.u[1] = pkbf(gelu_tanh(hA[2][2]+b1v[2][2]), gelu_tanh(hA[2][3]+b1v[2][3]));
      uu.u[2] = pkbf(gelu_tanh(hA[3][0]+b1v[3][0]), gelu_tanh(hA[3][1]+b1v[3][1]));
      uu.u[3] = pkbf(gelu_tanh(hA[3][2]+b1v[3][2]), gelu_tanh(hA[3][3]+b1v[3][3]));
      hfA1 = uu.h;
      uu.u[0] = pkbf(gelu_tanh(hB[0][0]+b1v[0][0]), gelu_tanh(hB[0][1]+b1v[0][1]));
      uu.u[1] = pkbf(gelu_tanh(hB[0][2]+b1v[0][2]), gelu_tanh(hB[0][3]+b1v[0][3]));
      uu.u[2] = pkbf(gelu_tanh(hB[1][0]+b1v[1][0]), gelu_tanh(hB[1][1]+b1v[1][1]));
      uu.u[3] = pkbf(gelu_tanh(hB[1][2]+b1v[1][2]), gelu_tanh(hB[1][3]+b1v[1][3]));
      hfB0 = uu.h;
      uu.u[0] = pkbf(gelu_tanh(hB[2][0]+b1v[2][0]), gelu_tanh(hB[2][1]+b1v[2][1]));
      uu.u[1] = pkbf(gelu_tanh(hB[2][2]+b1v[2][2]), gelu_tanh(hB[2][3]+b1v[2][3]));
      uu.u[2] = pkbf(gelu_tanh(hB[3][0]+b1v[3][0]), gelu_tanh(hB[3][1]+b1v[3][1]));
      uu.u[3] = pkbf(gelu_tanh(hB[3][2]+b1v[3][2]), gelu_tanh(hB[3][3]+b1v[3][3]));
      hfB1 = uu.h;
    }
    // W2: 16 tiles; 1 read -> 2 MFMAs
    #pragma unroll
    for (int hpl = 0; hpl < 2; ++hpl)
      #pragma unroll
      for (int m = 0; m < 8; ++m){
        bf16x8 a = *(const bf16x8*)(smem + curoff + 16384 + ((hpl*8 + m) << 10) + l * 16);
        acA[m] = MFMA32(a, hpl ? hfA1 : hfA0, acA[m]);
        acB[m] = MFMA32(a, hpl ? hfB1 : hfB0, acB[m]);
      }
    if (c < 7) __syncthreads();
  }

  // ---- epilogue: out = y (regs) + mlp + b2
  #pragma unroll
  for (int m = 0; m < 8; ++m){
    int c0 = m * 16 + 4 * lg;
    f32x4 b2v = *(const f32x4*)(b2 + c0);
    size_t baseA = ((size_t)(b * 128 + c0)) * HW + pix0 + pA;
    #pragma unroll
    for (int r = 0; r < 4; ++r){
      yout[baseA + (size_t)r * HW]      = yvA[m][r] + acA[m][r] + b2v[r];
      yout[baseA + 16 + (size_t)r * HW] = yvB[m][r] + acB[m][r] + b2v[r];
    }
  }
}

extern "C" void kernel_launch(void* const* d_in, const int* in_sizes, int n_in,
                              void* d_out, int out_size, void* d_ws, size_t ws_size,
                              hipStream_t stream)
{
  const float* x    = (const float*)d_in[0];
  const float* n1w  = (const float*)d_in[1];
  const float* n1b  = (const float*)d_in[2];
  const float* qkvw = (const float*)d_in[3];
  const float* qkvb = (const float*)d_in[4];
  const float* pw   = (const float*)d_in[5];
  const float* pb   = (const float*)d_in[6];
  const float* n2w  = (const float*)d_in[7];
  const float* n2b  = (const float*)d_in[8];
  const float* w1   = (const float*)d_in[9];
  const float* b1   = (const float*)d_in[10];
  const float* w2   = (const float*)d_in[11];
  const float* b2   = (const float*)d_in[12];

  u16* qkvp = (u16*)d_ws;                  // q/k/v planes, each [b][4][65536][32] = 128 MB
  u16* qbuf = qkvp;                        // q plane doubles as attention output
  u16* kbuf = qkvp + 67108864ull;
  u16* vbuf = qkvp + 134217728ull;
  u16* wf   = qkvp + 201326592ull;         // packed dense weights (384 KB)
  u16* wfq = wf;
  u16* wfp = wf + 49152;
  u16* wf1 = wf + 65536;
  u16* wf2 = wf + 131072;
  float* y = (float*)d_out;

  k_pack<<<384, 256, 0, stream>>>(qkvw, pw, w1, w2, wf);
  k_ln_qkv<<<8192, 256, 0, stream>>>(x, n1w, n1b, wfq, qkvb, qkvp);
  k_attn<<<8192, 256, 0, stream>>>(qbuf, kbuf, vbuf);
  k_proj_mlp<<<4096, 256, 0, stream>>>(qbuf, wfp, pb, x, n2w, n2b, wf1, b1, wf2, b2, y);
}